// Round 6
// baseline (734.837 us; speedup 1.0000x reference)
//
#include <hip/hip_runtime.h>
#include <hip/hip_cooperative_groups.h>
#include <math.h>

namespace cg = cooperative_groups;

#define TPB 256
#define NBK_MAX 512   // max dst buckets (128 nodes each)
#define FILL_CAP 4096 // LDS col-buffer per bucket (avg run 2046)
#define SC_CH 16      // register-held edges per thread in bscatter
#define SMEM_BYTES 34816  // = 64*(128+8)*2*2, the mm<128> hi/lo staging (max phase)

typedef short bf16x8 __attribute__((ext_vector_type(8)));
typedef float f32x4 __attribute__((ext_vector_type(4)));

__device__ __forceinline__ unsigned short rne_bf16(float f) {
  unsigned u = __float_as_uint(f);
  return (unsigned short)((u + 0x7fffu + ((u >> 16) & 1u)) >> 16);
}
__device__ __forceinline__ float bf16_f(unsigned short v) {
  return __uint_as_float((unsigned)v << 16);
}
__device__ __forceinline__ float rl_f(float v, int l) {
  return __int_as_float(__builtin_amdgcn_readlane(__float_as_int(v), l));
}

// ================= device phase bodies (shared by coop kernel & fallback) =================

// bucket histogram over dst (first GB blocks only)
__device__ void bcount_phase(const int* dst, int* btot, int E, int NBK,
                             int GB, int blk, char* smem) {
  int* hh = (int*)smem;
  int tid = threadIdx.x;
  for (int b = tid; b < NBK; b += TPB) hh[b] = 0;
  __syncthreads();
  int chunk = (E + GB - 1) / GB, lo = blk * chunk, hi = min(E, lo + chunk);
  for (int e = lo + tid; e < hi; e += TPB) atomicAdd(&hh[dst[e] >> 7], 1);
  __syncthreads();
  for (int b = tid; b < NBK; b += TPB)
    if (hh[b]) atomicAdd(&btot[b], hh[b]);
}

// split W[K][64] fp32 -> WT hi/lo [64][K] bf16, both layers (strided over GB blocks)
__device__ void wsplit_phase(const float* W1, const float* W2,
                             unsigned short* hi1, unsigned short* lo1,
                             unsigned short* hi2, unsigned short* lo2,
                             int GB, int blk) {
  for (int i = blk * TPB + threadIdx.x; i < 128 * 64 + 64 * 64; i += GB * TPB) {
    if (i < 128 * 64) {
      int k = i >> 6, n = i & 63;
      float w = W1[i];
      unsigned short hb = rne_bf16(w);
      hi1[n * 128 + k] = hb;
      lo1[n * 128 + k] = rne_bf16(w - bf16_f(hb));
    } else {
      int j = i - 128 * 64;
      int k = j >> 6, n = j & 63;
      float w = W2[j];
      unsigned short hb = rne_bf16(w);
      hi2[n * 64 + k] = hb;
      lo2[n * 64 + k] = rne_bf16(w - bf16_f(hb));
    }
  }
}

// exclusive scan of NBK bucket totals (single block). bstart[b] = e2 offset of
// bucket b; doubles as rowptr at node granularity b*128.
__device__ void bstart_phase(const int* btot, int* bstart, int* gcur,
                             int* rowptr, int NBK, int N, int E, char* smem) {
  int* sc = (int*)smem;
  int t = threadIdx.x;
  int i0 = 2 * t, i1 = 2 * t + 1;
  int a0 = (i0 < NBK) ? btot[i0] : 0;
  int a1 = (i1 < NBK) ? btot[i1] : 0;
  int s = a0 + a1;
  sc[t] = s;
  __syncthreads();
  for (int o = 1; o < TPB; o <<= 1) {
    int v = (t >= o) ? sc[t - o] : 0;
    __syncthreads();
    sc[t] += v;
    __syncthreads();
  }
  int excl = sc[t] - s;
  if (i0 < NBK) { bstart[i0] = excl;      gcur[i0] = excl; }
  if (i1 < NBK) { bstart[i1] = excl + a0; gcur[i1] = excl + a0; }
  if (t == 0) { bstart[NBK] = E; rowptr[N] = E; }
  __syncthreads();
}

// scatter edges into bucket-grouped e2 (atomic range-reservation per tile;
// each reserved range contiguous & single-block-written -> no line ping-pong)
__device__ void bscatter_phase(const int* src, const int* dst, int* gcur,
                               unsigned* e2, int E, int NBK,
                               int GB, int blk, char* smem) {
  int* hh = (int*)smem;
  int* base = hh + NBK_MAX;
  int tid = threadIdx.x;
  int chunk = (E + GB - 1) / GB, lo = blk * chunk, hi = min(E, lo + chunk);
  for (int t0 = lo; t0 < hi; t0 += TPB * SC_CH) {
    int sv[SC_CH], dv[SC_CH];
    for (int b = tid; b < NBK; b += TPB) hh[b] = 0;
    __syncthreads();
#pragma unroll
    for (int u = 0; u < SC_CH; ++u) {
      int e = t0 + u * TPB + tid;
      if (e < hi) {
        dv[u] = dst[e];
        sv[u] = src[e];
        atomicAdd(&hh[dv[u] >> 7], 1);
      } else {
        dv[u] = -1;
      }
    }
    __syncthreads();
    for (int b = tid; b < NBK; b += TPB) {
      int c = hh[b];
      base[b] = c ? atomicAdd(&gcur[b], c) : 0;
    }
    __syncthreads();
    for (int b = tid; b < NBK; b += TPB) hh[b] = 0;
    __syncthreads();
#pragma unroll
    for (int u = 0; u < SC_CH; ++u) {
      if (dv[u] >= 0) {
        int bk = dv[u] >> 7;
        int r = atomicAdd(&hh[bk], 1);
        e2[base[bk] + r] = ((unsigned)sv[u] << 7) | (unsigned)(dv[u] & 127);
      }
    }
    __syncthreads();
  }
}

// fused per-bucket count + local scan + rowptr/dinv + CSR fill (buckets grid-stride)
__device__ void build_phase(const unsigned* e2, const int* bstart, int* rowptr,
                            float* dinv, int* col, int N, int NBK, char* smem) {
  int* c = (int*)smem;
  int* sc = c + 128;
  int* cur = c + 256;
  int* buf = c + 384;
  int tid = threadIdx.x;
  for (int b = blockIdx.x; b < NBK; b += gridDim.x) {
    __syncthreads();  // protect LDS reuse across bucket iterations
    if (tid < 128) c[tid] = 0;
    __syncthreads();
    int st = bstart[b], en = bstart[b + 1], len = en - st;
    for (int i = st + tid; i < en; i += TPB) atomicAdd(&c[e2[i] & 127u], 1);
    __syncthreads();
    if (tid < 128) sc[tid] = c[tid];
    __syncthreads();
    for (int o = 1; o < 128; o <<= 1) {
      int v = (tid >= o && tid < 128) ? sc[tid - o] : 0;
      __syncthreads();
      if (tid < 128) sc[tid] += v;
      __syncthreads();
    }
    if (tid < 128) {
      int excl = sc[tid] - c[tid];
      cur[tid] = excl;
      int node = b * 128 + tid;
      if (node < N) {
        rowptr[node] = st + excl;
        dinv[node] = rsqrtf((float)(c[tid] + 1));  // +1 self-loop
      }
    }
    __syncthreads();
    if (len <= FILL_CAP) {
      for (int i = st + tid; i < en; i += TPB) {
        unsigned v = e2[i];
        int p2 = atomicAdd(&cur[v & 127u], 1);
        buf[p2] = (int)(v >> 7);
      }
      __syncthreads();
      for (int i = tid; i < len; i += TPB) col[st + i] = buf[i];
    } else {  // safety fallback
      for (int i = st + tid; i < en; i += TPB) {
        unsigned v = e2[i];
        int p2 = atomicAdd(&cur[v & 127u], 1);
        col[st + p2] = (int)(v >> 7);
      }
    }
  }
}

// MFMA GEMM: Hout[N,64](bf16) = A[N,K] @ W[K,64]; split-bf16 (residual ~2^-18).
// Stages W hi/lo once per block, then grid-strides 64-row tiles (4 waves x 16).
template <int K, bool AF32>
__device__ void mm_phase(const void* Ap, const unsigned short* WThi,
                         const unsigned short* WTlo, unsigned short* Hout,
                         int N, char* smem) {
  constexpr int P = K + 8;  // LDS pitch: conflict-free b128 frag reads
  unsigned short* sHi = (unsigned short*)smem;
  unsigned short* sLo = sHi + 64 * P;
  int tid = threadIdx.x;
  constexpr int CH = 64 * K / 8;
  for (int i = tid; i < CH; i += TPB) {
    int n = i / (K / 8), ko = i % (K / 8);
    *(int4*)(sHi + n * P + ko * 8) = *(const int4*)(WThi + n * K + ko * 8);
    *(int4*)(sLo + n * P + ko * 8) = *(const int4*)(WTlo + n * K + ko * 8);
  }
  __syncthreads();
  int wave = tid >> 6, lane = tid & 63;
  int oct = lane >> 4, l15 = lane & 15;
  for (int tb = blockIdx.x * 64; tb < N; tb += gridDim.x * 64) {
    int base = tb + wave * 16;
    int arow = base + l15;
    if (arow >= N) arow = N - 1;
    f32x4 acc[4] = {};
#pragma unroll
    for (int s = 0; s < K / 32; ++s) {
      bf16x8 ahi, alo;
      if (AF32) {
        const float* ap = (const float*)Ap + (size_t)arow * K + s * 32 + oct * 8;
        float4 f0 = *(const float4*)ap;
        float4 f1 = *(const float4*)(ap + 4);
        float fv[8] = {f0.x, f0.y, f0.z, f0.w, f1.x, f1.y, f1.z, f1.w};
#pragma unroll
        for (int j = 0; j < 8; ++j) {
          unsigned short hb = rne_bf16(fv[j]);
          ahi[j] = (short)hb;
          alo[j] = (short)rne_bf16(fv[j] - bf16_f(hb));
        }
      } else {
        ahi = *(const bf16x8*)((const unsigned short*)Ap + (size_t)arow * K + s * 32 + oct * 8);
      }
#pragma unroll
      for (int t = 0; t < 4; ++t) {
        bf16x8 bhi = *(const bf16x8*)(sHi + (t * 16 + l15) * P + s * 32 + oct * 8);
        bf16x8 blo = *(const bf16x8*)(sLo + (t * 16 + l15) * P + s * 32 + oct * 8);
        acc[t] = __builtin_amdgcn_mfma_f32_16x16x32_bf16(ahi, bhi, acc[t], 0, 0, 0);
        acc[t] = __builtin_amdgcn_mfma_f32_16x16x32_bf16(ahi, blo, acc[t], 0, 0, 0);
        if (AF32)
          acc[t] = __builtin_amdgcn_mfma_f32_16x16x32_bf16(alo, bhi, acc[t], 0, 0, 0);
      }
    }
#pragma unroll
    for (int r = 0; r < 4; ++r) {
      int row = base + oct * 4 + r;
      if (row < N) {
#pragma unroll
        for (int t = 0; t < 4; ++t)
          Hout[(size_t)row * 64 + t * 16 + l15] = rne_bf16(acc[t][r]);
      }
    }
  }
}

// pull aggregation: wave per node (grid-stride), lane = feature, 8-deep readlane batching
__device__ void agg_phase(const unsigned short* H, const int* rowptr,
                          const int* col, const float* dinv, const float* bias,
                          unsigned short* OUT, int N) {
  int wid = (blockIdx.x * TPB + threadIdx.x) >> 6;
  int gw = (gridDim.x * TPB) >> 6;
  int lane = threadIdx.x & 63;
  float bs = bias[lane];
  for (int i = wid; i < N; i += gw) {
    float di = dinv[i];
    float acc = bf16_f(H[((size_t)i << 6) + lane]) * di * di;  // self-loop
    int beg = rowptr[i], end = rowptr[i + 1];
    for (int c0 = beg; c0 < end; c0 += 64) {
      int m = end - c0;
      if (m > 64) m = 64;
      int jj = c0 + lane;
      int sv = col[jj < end ? jj : beg];
      float nv = di * dinv[sv];
      int t = 0;
      for (; t + 8 <= m; t += 8) {
        int s0 = __builtin_amdgcn_readlane(sv, t + 0);
        int s1 = __builtin_amdgcn_readlane(sv, t + 1);
        int s2 = __builtin_amdgcn_readlane(sv, t + 2);
        int s3 = __builtin_amdgcn_readlane(sv, t + 3);
        int s4 = __builtin_amdgcn_readlane(sv, t + 4);
        int s5 = __builtin_amdgcn_readlane(sv, t + 5);
        int s6 = __builtin_amdgcn_readlane(sv, t + 6);
        int s7 = __builtin_amdgcn_readlane(sv, t + 7);
        float h0 = bf16_f(H[((size_t)s0 << 6) + lane]);
        float h1 = bf16_f(H[((size_t)s1 << 6) + lane]);
        float h2 = bf16_f(H[((size_t)s2 << 6) + lane]);
        float h3 = bf16_f(H[((size_t)s3 << 6) + lane]);
        float h4 = bf16_f(H[((size_t)s4 << 6) + lane]);
        float h5 = bf16_f(H[((size_t)s5 << 6) + lane]);
        float h6 = bf16_f(H[((size_t)s6 << 6) + lane]);
        float h7 = bf16_f(H[((size_t)s7 << 6) + lane]);
        acc += h0 * rl_f(nv, t + 0);
        acc += h1 * rl_f(nv, t + 1);
        acc += h2 * rl_f(nv, t + 2);
        acc += h3 * rl_f(nv, t + 3);
        acc += h4 * rl_f(nv, t + 4);
        acc += h5 * rl_f(nv, t + 5);
        acc += h6 * rl_f(nv, t + 6);
        acc += h7 * rl_f(nv, t + 7);
      }
      if (t + 4 <= m) {
        int s0 = __builtin_amdgcn_readlane(sv, t + 0);
        int s1 = __builtin_amdgcn_readlane(sv, t + 1);
        int s2 = __builtin_amdgcn_readlane(sv, t + 2);
        int s3 = __builtin_amdgcn_readlane(sv, t + 3);
        float h0 = bf16_f(H[((size_t)s0 << 6) + lane]);
        float h1 = bf16_f(H[((size_t)s1 << 6) + lane]);
        float h2 = bf16_f(H[((size_t)s2 << 6) + lane]);
        float h3 = bf16_f(H[((size_t)s3 << 6) + lane]);
        acc += h0 * rl_f(nv, t + 0);
        acc += h1 * rl_f(nv, t + 1);
        acc += h2 * rl_f(nv, t + 2);
        acc += h3 * rl_f(nv, t + 3);
        t += 4;
      }
      for (; t < m; ++t) {
        int s = __builtin_amdgcn_readlane(sv, t);
        acc += bf16_f(H[((size_t)s << 6) + lane]) * rl_f(nv, t);
      }
    }
    OUT[((size_t)i << 6) + lane] = rne_bf16(tanhf(acc + bs));
  }
}

// MLP head: one thread per node, A-row (64 bf16) in registers, W1^T broadcast from LDS
__device__ void fc_phase(const unsigned short* A, const float* w1,
                         const float* b1, const float* w2, const float* b2,
                         float* out, int N, char* smem) {
  float* sw1t = (float*)smem;        // [32][64]
  float* sb1 = sw1t + 32 * 64;
  float* sw2 = sb1 + 32;
  int tid = threadIdx.x;
  for (int i = tid; i < 32 * 64; i += TPB) {
    int j = i >> 6, k = i & 63;
    sw1t[i] = w1[k * 32 + j];
  }
  if (tid < 32) { sb1[tid] = b1[tid]; sw2[tid] = w2[tid]; }
  __syncthreads();
  float bb = b2[0];
  for (int node = blockIdx.x * TPB + tid; node < N; node += gridDim.x * TPB) {
    uint4 rv[8];
    const uint4* ap = (const uint4*)(A + (size_t)node * 64);
#pragma unroll
    for (int q = 0; q < 8; ++q) rv[q] = ap[q];
    float o = 0.f;
    for (int j = 0; j < 32; ++j) {
      const float* wr = sw1t + j * 64;
      float accj = sb1[j];
#pragma unroll
      for (int q = 0; q < 8; ++q) {
        unsigned u0 = rv[q].x, u1 = rv[q].y, u2 = rv[q].z, u3 = rv[q].w;
        accj += __uint_as_float(u0 << 16) * wr[8 * q + 0] +
                __uint_as_float(u0 & 0xffff0000u) * wr[8 * q + 1];
        accj += __uint_as_float(u1 << 16) * wr[8 * q + 2] +
                __uint_as_float(u1 & 0xffff0000u) * wr[8 * q + 3];
        accj += __uint_as_float(u2 << 16) * wr[8 * q + 4] +
                __uint_as_float(u2 & 0xffff0000u) * wr[8 * q + 5];
        accj += __uint_as_float(u3 << 16) * wr[8 * q + 6] +
                __uint_as_float(u3 & 0xffff0000u) * wr[8 * q + 7];
      }
      o += tanhf(accj) * sw2[j];
    }
    out[node] = o + bb;
  }
}

// ================= the single cooperative kernel =================

struct KParams {
  const float* x;
  const int* src;
  const int* dst;
  const float* w1;
  const float* b1;
  const float* w2;
  const float* b2;
  const float* fw1;
  const float* fb1;
  const float* fw2;
  const float* fb2;
  float* out;
  int* btot;
  int* bstart;
  int* gcur;
  int* rowptr;
  float* dinv;
  unsigned* e2;
  int* col;
  unsigned short* wt1hi;
  unsigned short* wt1lo;
  unsigned short* wt2hi;
  unsigned short* wt2lo;
  unsigned short* hbuf;
  unsigned short* abuf;
  int N, E, NBK;
};

__global__ __launch_bounds__(TPB, 4) void k_all(KParams p) {
  __shared__ __align__(16) char smem[SMEM_BYTES];
  cg::grid_group grid = cg::this_grid();
  const int blk = blockIdx.x;
  const int G = gridDim.x;
  const int GB = (G < 256) ? G : 256;  // edge-pass blocks (write-locality cap)

  // P0: zero bucket totals
  if (blk == 0)
    for (int b = threadIdx.x; b < p.NBK; b += TPB) p.btot[b] = 0;
  grid.sync();

  // P1: bucket histogram + weight split
  if (blk < GB) {
    bcount_phase(p.dst, p.btot, p.E, p.NBK, GB, blk, smem);
    wsplit_phase(p.w1, p.w2, p.wt1hi, p.wt1lo, p.wt2hi, p.wt2lo, GB, blk);
  }
  grid.sync();

  // P2: bucket-start scan (block 0) + mm1 (all blocks; independent of build)
  if (blk == 0)
    bstart_phase(p.btot, p.bstart, p.gcur, p.rowptr, p.NBK, p.N, p.E, smem);
  mm_phase<128, true>(p.x, p.wt1hi, p.wt1lo, p.hbuf, p.N, smem);
  grid.sync();

  // P3: scatter edges into bucket-grouped e2
  if (blk < GB)
    bscatter_phase(p.src, p.dst, p.gcur, p.e2, p.E, p.NBK, GB, blk, smem);
  grid.sync();

  // P4: per-bucket CSR finalize (rowptr/dinv/col)
  build_phase(p.e2, p.bstart, p.rowptr, p.dinv, p.col, p.N, p.NBK, smem);
  grid.sync();

  // P5: layer-1 aggregation + tanh
  agg_phase(p.hbuf, p.rowptr, p.col, p.dinv, p.b1, p.abuf, p.N);
  grid.sync();

  // P6: layer-2 GEMM
  mm_phase<64, false>(p.abuf, p.wt2hi, p.wt2lo, p.hbuf, p.N, smem);
  grid.sync();

  // P7: layer-2 aggregation + tanh
  agg_phase(p.hbuf, p.rowptr, p.col, p.dinv, p.b2, p.abuf, p.N);
  grid.sync();

  // P8: MLP head
  fc_phase(p.abuf, p.fw1, p.fb1, p.fw2, p.fb2, p.out, p.N, smem);
}

// ================= fallback multi-kernel wrappers (if coop launch unavailable) =================

__global__ __launch_bounds__(TPB) void kf_bcount(const int* dst, int* btot, int E, int NBK) {
  __shared__ __align__(16) char smem[NBK_MAX * 4];
  bcount_phase(dst, btot, E, NBK, gridDim.x, blockIdx.x, smem);
}
__global__ __launch_bounds__(TPB) void kf_wsplit(const float* w1, const float* w2,
                                                 unsigned short* a, unsigned short* b,
                                                 unsigned short* c, unsigned short* d) {
  wsplit_phase(w1, w2, a, b, c, d, gridDim.x, blockIdx.x);
}
__global__ __launch_bounds__(TPB) void kf_bstart(const int* btot, int* bstart, int* gcur,
                                                 int* rowptr, int NBK, int N, int E) {
  __shared__ __align__(16) char smem[TPB * 4];
  bstart_phase(btot, bstart, gcur, rowptr, NBK, N, E, smem);
}
__global__ __launch_bounds__(TPB) void kf_bscatter(const int* src, const int* dst, int* gcur,
                                                   unsigned* e2, int E, int NBK) {
  __shared__ __align__(16) char smem[NBK_MAX * 8];
  bscatter_phase(src, dst, gcur, e2, E, NBK, gridDim.x, blockIdx.x, smem);
}
__global__ __launch_bounds__(TPB) void kf_build(const unsigned* e2, const int* bstart,
                                                int* rowptr, float* dinv, int* col,
                                                int N, int NBK) {
  __shared__ __align__(16) char smem[(384 + FILL_CAP) * 4];
  build_phase(e2, bstart, rowptr, dinv, col, N, NBK, smem);
}
__global__ __launch_bounds__(TPB) void kf_mm128(const float* X, const unsigned short* hi,
                                                const unsigned short* lo, unsigned short* H, int N) {
  __shared__ __align__(16) char smem[SMEM_BYTES];
  mm_phase<128, true>(X, hi, lo, H, N, smem);
}
__global__ __launch_bounds__(TPB) void kf_mm64(const unsigned short* X, const unsigned short* hi,
                                               const unsigned short* lo, unsigned short* H, int N) {
  __shared__ __align__(16) char smem[64 * 72 * 2 * 2];
  mm_phase<64, false>(X, hi, lo, H, N, smem);
}
__global__ __launch_bounds__(TPB) void kf_agg(const unsigned short* H, const int* rowptr,
                                              const int* col, const float* dinv,
                                              const float* bias, unsigned short* OUT, int N) {
  agg_phase(H, rowptr, col, dinv, bias, OUT, N);
}
__global__ __launch_bounds__(TPB) void kf_fc(const unsigned short* A, const float* w1,
                                             const float* b1, const float* w2,
                                             const float* b2, float* out, int N) {
  __shared__ __align__(16) char smem[(32 * 64 + 64) * 4];
  fc_phase(A, w1, b1, w2, b2, out, N, smem);
}

// ================= host =================

extern "C" void kernel_launch(void* const* d_in, const int* in_sizes, int n_in,
                              void* d_out, int out_size, void* d_ws, size_t ws_size,
                              hipStream_t stream) {
  KParams p;
  p.x   = (const float*)d_in[0];
  const int* ei = (const int*)d_in[1];
  p.w1  = (const float*)d_in[2];
  p.b1  = (const float*)d_in[3];
  p.w2  = (const float*)d_in[4];
  p.b2  = (const float*)d_in[5];
  p.fw1 = (const float*)d_in[6];
  p.fb1 = (const float*)d_in[7];
  p.fw2 = (const float*)d_in[8];
  p.fb2 = (const float*)d_in[9];
  p.out = (float*)d_out;

  p.N = in_sizes[0] / 128;
  p.E = in_sizes[1] / 2;
  p.src = ei;
  p.dst = ei + p.E;
  p.NBK = (p.N + 127) / 128;

  char* wp = (char*)d_ws;
  size_t off = 0;
  auto take = [&](size_t bytes) -> void* {
    void* r = wp + off;
    off += (bytes + 255) & ~(size_t)255;
    return r;
  };
  p.btot   = (int*)take((size_t)p.NBK * 4);
  p.bstart = (int*)take((size_t)(p.NBK + 1) * 4);
  p.gcur   = (int*)take((size_t)p.NBK * 4);
  p.rowptr = (int*)take((size_t)(p.N + 1) * 4);
  p.dinv   = (float*)take((size_t)p.N * 4);
  p.e2     = (unsigned*)take((size_t)p.E * 4);
  p.col    = (int*)take((size_t)p.E * 4);
  p.wt1hi  = (unsigned short*)take(64 * 128 * 2);
  p.wt1lo  = (unsigned short*)take(64 * 128 * 2);
  p.wt2hi  = (unsigned short*)take(64 * 64 * 2);
  p.wt2lo  = (unsigned short*)take(64 * 64 * 2);
  p.hbuf   = (unsigned short*)take((size_t)p.N * 64 * 2);
  p.abuf   = (unsigned short*)take((size_t)p.N * 64 * 2);
  (void)ws_size; (void)n_in; (void)out_size;

  // cooperative single-launch path
  int maxb = 0;
  hipError_t oe = hipOccupancyMaxActiveBlocksPerMultiprocessor(&maxb, k_all, TPB, 0);
  if (oe != hipSuccess || maxb < 1) maxb = 1;
  int nblk = maxb * 256;  // 256 CUs on MI355X
  if (nblk > 1024) nblk = 1024;
  void* args[] = {(void*)&p};
  hipError_t err = hipLaunchCooperativeKernel((const void*)k_all, dim3(nblk), dim3(TPB),
                                              args, 0, stream);
  if (err == hipSuccess) return;

  // fallback: multi-kernel path (same phase bodies)
  hipMemsetAsync(p.btot, 0, (size_t)p.NBK * 4, stream);
  kf_bcount<<<256, TPB, 0, stream>>>(p.dst, p.btot, p.E, p.NBK);
  kf_wsplit<<<64, TPB, 0, stream>>>(p.w1, p.w2, p.wt1hi, p.wt1lo, p.wt2hi, p.wt2lo);
  kf_bstart<<<1, TPB, 0, stream>>>(p.btot, p.bstart, p.gcur, p.rowptr, p.NBK, p.N, p.E);
  kf_bscatter<<<256, TPB, 0, stream>>>(p.src, p.dst, p.gcur, p.e2, p.E, p.NBK);
  kf_build<<<p.NBK, TPB, 0, stream>>>(p.e2, p.bstart, p.rowptr, p.dinv, p.col, p.N, p.NBK);
  int gmm = (p.N + 63) / 64;
  kf_mm128<<<gmm, TPB, 0, stream>>>(p.x, p.wt1hi, p.wt1lo, p.hbuf, p.N);
  kf_agg<<<(p.N + 3) / 4, TPB, 0, stream>>>(p.hbuf, p.rowptr, p.col, p.dinv, p.b1, p.abuf, p.N);
  kf_mm64<<<gmm, TPB, 0, stream>>>(p.abuf, p.wt2hi, p.wt2lo, p.hbuf, p.N);
  kf_agg<<<(p.N + 3) / 4, TPB, 0, stream>>>(p.hbuf, p.rowptr, p.col, p.dinv, p.b2, p.abuf, p.N);
  kf_fc<<<(p.N + 255) / 256, TPB, 0, stream>>>(p.abuf, p.fw1, p.fb1, p.fw2, p.fb2, p.out, p.N);
}

// Round 7
// 237.633 us; speedup vs baseline: 3.0923x; 3.0923x over previous
//
#include <hip/hip_runtime.h>
#include <math.h>

#define TPB 256
#define NBK_MAX 512   // max dst buckets (128 nodes each)
#define FILL_CAP 4096 // LDS col-buffer per bucket (avg run 2046, max ~2300)
#define SC_CH 16      // register-held edges per thread in bscatter

typedef short bf16x8 __attribute__((ext_vector_type(8)));
typedef float f32x4 __attribute__((ext_vector_type(4)));

__device__ __forceinline__ unsigned short rne_bf16(float f) {
  unsigned u = __float_as_uint(f);
  return (unsigned short)((u + 0x7fffu + ((u >> 16) & 1u)) >> 16);
}
__device__ __forceinline__ float bf16_f(unsigned short v) {
  return __uint_as_float((unsigned)v << 16);
}
__device__ __forceinline__ float blo(unsigned u) { return __uint_as_float(u << 16); }
__device__ __forceinline__ float bhi(unsigned u) { return __uint_as_float(u & 0xffff0000u); }

// ---------------- build 1: bucket totals ----------------
__global__ __launch_bounds__(TPB) void k_bcount(const int* __restrict__ dst,
                                                int* __restrict__ btot, int E, int NBK) {
  __shared__ int h[NBK_MAX];
  int tid = threadIdx.x, blk = blockIdx.x, G = gridDim.x;
  for (int b = tid; b < NBK; b += TPB) h[b] = 0;
  __syncthreads();
  int chunk = (E + G - 1) / G, lo = blk * chunk, hi = min(E, lo + chunk);
  for (int e = lo + tid; e < hi; e += TPB) atomicAdd(&h[dst[e] >> 7], 1);
  __syncthreads();
  for (int b = tid; b < NBK; b += TPB)
    if (h[b]) atomicAdd(&btot[b], h[b]);
}

// ---------------- build 2: exclusive scan of bucket totals (1 block) ----------------
__global__ __launch_bounds__(TPB) void k_bstart(const int* __restrict__ btot,
                                                int* __restrict__ bstart,
                                                int* __restrict__ gcur,
                                                int* __restrict__ rowptr,
                                                int NBK, int N, int E) {
  __shared__ int sc[TPB];
  int t = threadIdx.x;
  int i0 = 2 * t, i1 = 2 * t + 1;
  int a0 = (i0 < NBK) ? btot[i0] : 0;
  int a1 = (i1 < NBK) ? btot[i1] : 0;
  int s = a0 + a1;
  sc[t] = s;
  __syncthreads();
  for (int o = 1; o < TPB; o <<= 1) {
    int v = (t >= o) ? sc[t - o] : 0;
    __syncthreads();
    sc[t] += v;
    __syncthreads();
  }
  int excl = sc[t] - s;
  if (i0 < NBK) { bstart[i0] = excl;      gcur[i0] = excl; }
  if (i1 < NBK) { bstart[i1] = excl + a0; gcur[i1] = excl + a0; }
  if (t == 0) { bstart[NBK] = E; rowptr[N] = E; }
}

// ---------------- build 3: scatter edges into bucket-grouped e2 ----------------
// atomic range-reservation per tile; each run contiguous & single-block-written
__global__ __launch_bounds__(TPB) void k_bscatter(const int* __restrict__ src,
                                                  const int* __restrict__ dst,
                                                  int* __restrict__ gcur,
                                                  unsigned* __restrict__ e2,
                                                  int E, int NBK) {
  __shared__ int h[NBK_MAX];
  __shared__ int base[NBK_MAX];
  int tid = threadIdx.x, blk = blockIdx.x, G = gridDim.x;
  int chunk = (E + G - 1) / G, lo = blk * chunk, hi = min(E, lo + chunk);
  for (int t0 = lo; t0 < hi; t0 += TPB * SC_CH) {
    int sv[SC_CH], dv[SC_CH];
    for (int b = tid; b < NBK; b += TPB) h[b] = 0;
    __syncthreads();
#pragma unroll
    for (int u = 0; u < SC_CH; ++u) {
      int e = t0 + u * TPB + tid;
      if (e < hi) {
        dv[u] = dst[e];
        sv[u] = src[e];
        atomicAdd(&h[dv[u] >> 7], 1);
      } else {
        dv[u] = -1;
      }
    }
    __syncthreads();
    for (int b = tid; b < NBK; b += TPB) {
      int c = h[b];
      base[b] = c ? atomicAdd(&gcur[b], c) : 0;
    }
    __syncthreads();
    for (int b = tid; b < NBK; b += TPB) h[b] = 0;
    __syncthreads();
#pragma unroll
    for (int u = 0; u < SC_CH; ++u) {
      if (dv[u] >= 0) {
        int bk = dv[u] >> 7;
        int r = atomicAdd(&h[bk], 1);
        e2[base[bk] + r] = ((unsigned)sv[u] << 7) | (unsigned)(dv[u] & 127);
      }
    }
    __syncthreads();
  }
}

// ---------------- build 4: per-bucket count + local scan + rowptr/dinv + CSR fill ----------------
__global__ __launch_bounds__(TPB) void k_build(const unsigned* __restrict__ e2,
                                               const int* __restrict__ bstart,
                                               int* __restrict__ rowptr,
                                               float* __restrict__ dinv,
                                               int* __restrict__ col, int N) {
  __shared__ int c[128], sc[128], cur[128];
  __shared__ int buf[FILL_CAP];
  int tid = threadIdx.x, b = blockIdx.x;
  int st = bstart[b], en = bstart[b + 1], len = en - st;
  if (tid < 128) c[tid] = 0;
  __syncthreads();
  for (int i = st + tid; i < en; i += TPB) atomicAdd(&c[e2[i] & 127u], 1);
  __syncthreads();
  if (tid < 128) sc[tid] = c[tid];
  __syncthreads();
  for (int o = 1; o < 128; o <<= 1) {
    int v = (tid >= o && tid < 128) ? sc[tid - o] : 0;
    __syncthreads();
    if (tid < 128) sc[tid] += v;
    __syncthreads();
  }
  if (tid < 128) {
    int excl = sc[tid] - c[tid];
    cur[tid] = excl;
    int node = b * 128 + tid;
    if (node < N) {
      rowptr[node] = st + excl;
      dinv[node] = rsqrtf((float)(c[tid] + 1));  // +1 self-loop
    }
  }
  __syncthreads();
  if (len <= FILL_CAP) {
    for (int i = st + tid; i < en; i += TPB) {
      unsigned v = e2[i];
      int p = atomicAdd(&cur[v & 127u], 1);
      buf[p] = (int)(v >> 7);
    }
    __syncthreads();
    for (int i = tid; i < len; i += TPB) col[st + i] = buf[i];
  } else {  // safety fallback
    for (int i = st + tid; i < en; i += TPB) {
      unsigned v = e2[i];
      int p = atomicAdd(&cur[v & 127u], 1);
      col[st + p] = (int)(v >> 7);
    }
  }
}

// ---------------- MFMA GEMM with in-kernel W split (fp32 W -> hi/lo LDS) ----------------
// Hout[N,64](bf16) = A[N,K] @ W[K,64]; split-bf16: Ahi*Whi + Ahi*Wlo + Alo*Whi.
template <int K, bool AF32>
__global__ __launch_bounds__(TPB) void k_mm(const void* __restrict__ Ap,
                                            const float* __restrict__ W,
                                            unsigned short* __restrict__ Hout, int N) {
  constexpr int P = K + 8;  // LDS pitch: conflict-free b128 frag reads
  __shared__ unsigned short sHi[64 * P];
  __shared__ unsigned short sLo[64 * P];
  int tid = threadIdx.x;
  // stage + transpose + split: W[k][n] fp32 -> sHi/sLo[n][k] bf16
  for (int i = tid; i < K * 64; i += TPB) {
    int k = i >> 6, n = i & 63;  // coalesced read of W
    float w = W[i];
    unsigned short hb = rne_bf16(w);
    sHi[n * P + k] = hb;
    sLo[n * P + k] = rne_bf16(w - bf16_f(hb));
  }
  __syncthreads();
  int wave = tid >> 6, lane = tid & 63;
  int oct = lane >> 4, l15 = lane & 15;
  int base = blockIdx.x * 64 + wave * 16;
  int arow = base + l15;
  if (arow >= N) arow = N - 1;
  f32x4 acc[4] = {};
#pragma unroll
  for (int s = 0; s < K / 32; ++s) {
    bf16x8 ahi, alo;
    if (AF32) {
      const float* ap = (const float*)Ap + (size_t)arow * K + s * 32 + oct * 8;
      float4 f0 = *(const float4*)ap;
      float4 f1 = *(const float4*)(ap + 4);
      float fv[8] = {f0.x, f0.y, f0.z, f0.w, f1.x, f1.y, f1.z, f1.w};
#pragma unroll
      for (int j = 0; j < 8; ++j) {
        unsigned short hb = rne_bf16(fv[j]);
        ahi[j] = (short)hb;
        alo[j] = (short)rne_bf16(fv[j] - bf16_f(hb));
      }
    } else {
      ahi = *(const bf16x8*)((const unsigned short*)Ap + (size_t)arow * K + s * 32 + oct * 8);
    }
#pragma unroll
    for (int t = 0; t < 4; ++t) {
      bf16x8 bhi = *(const bf16x8*)(sHi + (t * 16 + l15) * P + s * 32 + oct * 8);
      bf16x8 blo = *(const bf16x8*)(sLo + (t * 16 + l15) * P + s * 32 + oct * 8);
      acc[t] = __builtin_amdgcn_mfma_f32_16x16x32_bf16(ahi, bhi, acc[t], 0, 0, 0);
      acc[t] = __builtin_amdgcn_mfma_f32_16x16x32_bf16(ahi, blo, acc[t], 0, 0, 0);
      if (AF32)
        acc[t] = __builtin_amdgcn_mfma_f32_16x16x32_bf16(alo, bhi, acc[t], 0, 0, 0);
    }
  }
#pragma unroll
  for (int r = 0; r < 4; ++r) {
    int row = base + oct * 4 + r;
    if (row < N) {
#pragma unroll
      for (int t = 0; t < 4; ++t)
        Hout[(size_t)row * 64 + t * 16 + l15] = rne_bf16(acc[t][r]);
    }
  }
}

// ---------------- per-node aggregation body ----------------
// Wave computes one node. Lane layout: q=lane&15 (feature quad), ep=lane>>4
// (edge phase): each uint2 load covers 4 bf16 feats of edge t+g*4+ep ->
// 4 edge-rows per load instruction, 16 rows in flight. Returns post-tanh
// feature value for feature = lane.
__device__ __forceinline__ float agg_node(int i, const unsigned short* __restrict__ H,
                                          const int* __restrict__ rowptr,
                                          const int* __restrict__ col,
                                          const float* __restrict__ dinv,
                                          float bfeat) {
  int lane = threadIdx.x & 63;
  int q = lane & 15, ep = lane >> 4;
  float di = dinv[i];
  // self-loop (only phase 0 weights it; others multiply by 0)
  uint2 sf = *(const uint2*)(H + ((size_t)i << 6) + q * 4);
  float w0 = (ep == 0) ? di * di : 0.f;
  float ax = w0 * blo(sf.x), ay = w0 * bhi(sf.x);
  float az = w0 * blo(sf.y), aw = w0 * bhi(sf.y);
  int beg = rowptr[i], end = rowptr[i + 1];
  for (int c0 = beg; c0 < end; c0 += 64) {
    int m = end - c0;
    if (m > 64) m = 64;
    int jj = c0 + lane;
    int sv = col[jj < end ? jj : beg];   // padded lanes hold a valid node id
    float nv = di * dinv[sv];
    for (int t = 0; t < m; t += 16) {
      uint2 hv[4];
      float wv[4];
#pragma unroll
      for (int g = 0; g < 4; ++g) {
        int e = t + g * 4 + ep;          // <= 63 always
        int s = __shfl(sv, e);
        float w = __shfl(nv, e);
        wv[g] = (e < m) ? w : 0.f;
        hv[g] = *(const uint2*)(H + ((size_t)s << 6) + q * 4);
      }
#pragma unroll
      for (int g = 0; g < 4; ++g) {
        float w = wv[g];
        ax += w * blo(hv[g].x);
        ay += w * bhi(hv[g].x);
        az += w * blo(hv[g].y);
        aw += w * bhi(hv[g].y);
      }
    }
  }
  // reduce over edge phases (lane bits 4,5)
#pragma unroll
  for (int o = 16; o < 64; o <<= 1) {
    ax += __shfl_xor(ax, o);
    ay += __shfl_xor(ay, o);
    az += __shfl_xor(az, o);
    aw += __shfl_xor(aw, o);
  }
  // transpose to feature-per-lane: feature f=lane lives in quad f>>2, elem f&3
  int srcl = lane >> 2;
  float v0 = __shfl(ax, srcl);
  float v1 = __shfl(ay, srcl);
  float v2 = __shfl(az, srcl);
  float v3 = __shfl(aw, srcl);
  float va = (lane & 1) ? v1 : v0;
  float vb = (lane & 1) ? v3 : v2;
  float v = (lane & 2) ? vb : va;
  return tanhf(v + bfeat);
}

// ---------------- aggregation kernel; DOFC fuses the MLP head ----------------
template <bool DOFC>
__global__ __launch_bounds__(TPB) void k_agg(const unsigned short* __restrict__ H,
                                             const int* __restrict__ rowptr,
                                             const int* __restrict__ col,
                                             const float* __restrict__ dinv,
                                             const float* __restrict__ bias,
                                             unsigned short* __restrict__ OUT,
                                             const float* __restrict__ fw1,
                                             const float* __restrict__ fb1,
                                             const float* __restrict__ fw2,
                                             const float* __restrict__ fb2,
                                             float* __restrict__ fout, int N) {
  __shared__ float sw1t[32 * 64];  // [j][k], only used when DOFC
  __shared__ float sb1[32];
  __shared__ float sw2[32];
  __shared__ float sA[4 * 64];
  int tid = threadIdx.x;
  int wid = tid >> 6, lane = tid & 63;
  float bfeat = bias[lane];
  if (DOFC) {
    for (int i = tid; i < 32 * 64; i += TPB) {
      int j = i >> 6, k = i & 63;
      sw1t[i] = fw1[k * 32 + j];
    }
    if (tid < 32) { sb1[tid] = fb1[tid]; sw2[tid] = fw2[tid]; }
    __syncthreads();
  }
  if (!DOFC) {
    int i = (blockIdx.x * TPB + tid) >> 6;
    if (i < N)
      OUT[((size_t)i << 6) + lane] = rne_bf16(agg_node(i, H, rowptr, col, dinv, bfeat));
    return;
  }
  // DOFC: block-synchronous 4-node groups, FC head from LDS (fp32 A, no abuf)
  int ngroups = (N + 3) / 4;
  float b2v = fb2[0];
  for (int grp = blockIdx.x; grp < ngroups; grp += gridDim.x) {
    int i = grp * 4 + wid;
    float aval = 0.f;
    if (i < N) aval = agg_node(i, H, rowptr, col, dinv, bfeat);
    sA[wid * 64 + lane] = aval;
    __syncthreads();
    if (tid < 128) {
      int n = tid >> 5, j = tid & 31;
      int node = grp * 4 + n;
      if (node < N) {
        float acc = sb1[j];
        const float4* ar = (const float4*)(sA + n * 64);
        const float* wr = sw1t + j * 64;
#pragma unroll
        for (int k4 = 0; k4 < 16; ++k4) {
          float4 av = ar[k4];
          acc += av.x * wr[4 * k4 + 0] + av.y * wr[4 * k4 + 1] +
                 av.z * wr[4 * k4 + 2] + av.w * wr[4 * k4 + 3];
        }
        float t = tanhf(acc) * sw2[j];
#pragma unroll
        for (int o = 1; o < 32; o <<= 1) t += __shfl_xor(t, o);
        if (j == 0) fout[node] = t + b2v;
      }
    }
    __syncthreads();
  }
}

// ================= host =================

extern "C" void kernel_launch(void* const* d_in, const int* in_sizes, int n_in,
                              void* d_out, int out_size, void* d_ws, size_t ws_size,
                              hipStream_t stream) {
  const float* x   = (const float*)d_in[0];
  const int*   ei  = (const int*)d_in[1];
  const float* w1  = (const float*)d_in[2];
  const float* b1  = (const float*)d_in[3];
  const float* w2  = (const float*)d_in[4];
  const float* b2  = (const float*)d_in[5];
  const float* fw1 = (const float*)d_in[6];
  const float* fb1 = (const float*)d_in[7];
  const float* fw2 = (const float*)d_in[8];
  const float* fb2 = (const float*)d_in[9];
  float* out = (float*)d_out;

  int N = in_sizes[0] / 128;
  int E = in_sizes[1] / 2;
  const int* src = ei;
  const int* dst = ei + E;

  const int G   = 256;                // blocks for edge passes (write locality)
  const int NBK = (N + 127) / 128;    // 391 buckets

  char* p = (char*)d_ws;
  size_t off = 0;
  auto take = [&](size_t bytes) -> void* {
    void* r = p + off;
    off += (bytes + 255) & ~(size_t)255;
    return r;
  };
  int*            btot   = (int*)take((size_t)NBK * 4);
  int*            bstart = (int*)take((size_t)(NBK + 1) * 4);
  int*            gcur   = (int*)take((size_t)NBK * 4);
  int*            rowptr = (int*)take((size_t)(N + 1) * 4);
  float*          dinv   = (float*)take((size_t)N * 4);
  unsigned*       e2     = (unsigned*)take((size_t)E * 4);
  int*            col    = (int*)take((size_t)E * 4);
  unsigned short* h      = (unsigned short*)take((size_t)N * 64 * 2);
  unsigned short* a      = (unsigned short*)take((size_t)N * 64 * 2);
  (void)ws_size; (void)n_in; (void)out_size;

  // graph build: 4 kernels + tiny memset
  hipMemsetAsync(btot, 0, (size_t)NBK * 4, stream);
  k_bcount<<<G, TPB, 0, stream>>>(dst, btot, E, NBK);
  k_bstart<<<1, TPB, 0, stream>>>(btot, bstart, gcur, rowptr, NBK, N, E);
  k_bscatter<<<G, TPB, 0, stream>>>(src, dst, gcur, e2, E, NBK);
  k_build<<<NBK, TPB, 0, stream>>>(e2, bstart, rowptr, dinv, col, N);

  // network
  int gmm = (N + 63) / 64;
  k_mm<128, true><<<gmm, TPB, 0, stream>>>(x, w1, h, N);
  k_agg<false><<<(N + 3) / 4, TPB, 0, stream>>>(h, rowptr, col, dinv, b1, a,
                                                nullptr, nullptr, nullptr, nullptr,
                                                nullptr, N);
  k_mm<64, false><<<gmm, TPB, 0, stream>>>(a, w2, h, N);
  k_agg<true><<<1536, TPB, 0, stream>>>(h, rowptr, col, dinv, b2, nullptr,
                                        fw1, fb1, fw2, fb2, out, N);
}